// Round 8
// baseline (1013.698 us; speedup 1.0000x reference)
//
#include <hip/hip_runtime.h>
#include <hip/hip_bf16.h>

// BatchTripletLoss on MI355X — round 8: 2 blocks/CU co-residency.
// 256^2 triangular blocks (bn>=bm), 8 waves (2M x 4N), 16x16x32 MFMA.
// BK=32, prefetch-1 double buffer -> LDS 64KB -> 2 blocks/CU (16 waves/CU):
// cross-block overlap fills MFMA/LDS/barrier stalls + kills the 3-round tail.
// Per KT: {stage(kt+1 -> other buf); 12 ds_reads; 32 MFMA; __syncthreads()}.
// Swizzle: phys chunk = r*4 + (c ^ ((r>>1)&3)) — octet-conflict-free for b128
// frag reads (even lanes cover quads 0-3, odd lanes 4-7). Pre-permuted global
// source keeps the LDS dest linear (gload_lds constraint).

#define NROWS 8192
#define DIM   1024
#define BT    256
#define BK    32
#define NKT   (DIM / BK)            // 32 K-tiles
#define NBT   (NROWS / BT)          // 32 tile-rows
#define NTRI  (NBT * (NBT + 1) / 2) // 528 blocks

constexpr float EPS = 1e-6f;
constexpr float MARGIN = 0.5f;

typedef __attribute__((ext_vector_type(8))) short short8;
typedef __attribute__((ext_vector_type(4))) float f32x4;

__device__ __forceinline__ unsigned short f2bf_rne(float f) {
    unsigned u = __float_as_uint(f);
    u += 0x7fffu + ((u >> 16) & 1u);
    return (unsigned short)(u >> 16);
}

// ---------------- kernel 1: per-row stats + bf16 conversion ----------------
__global__ void prep_kernel(const float* __restrict__ X, const float* __restrict__ P,
                            unsigned short* __restrict__ Xb,
                            float* __restrict__ cj, float* __restrict__ basei,
                            float* __restrict__ posd, int* __restrict__ valid)
{
    const int tid  = threadIdx.x;
    const int w    = tid >> 6;
    const int lane = tid & 63;
    const int row  = blockIdx.x * 4 + w;
    const float* xr = X + (size_t)row * DIM;

    float sq = 0.f, sm = 0.f, pd = 0.f;
    bool eq = true;
    #pragma unroll
    for (int it = 0; it < 4; ++it) {
        const int idx = it * 256 + lane * 4;
        const float4 x = *(const float4*)(xr + idx);
        const float4 p = *(const float4*)(P + idx);
        sq += x.x*x.x + x.y*x.y + x.z*x.z + x.w*x.w;
        sm += x.x + x.y + x.z + x.w;
        const float d0 = x.x - p.x + EPS, d1 = x.y - p.y + EPS;
        const float d2 = x.z - p.z + EPS, d3 = x.w - p.w + EPS;
        pd += d0*d0 + d1*d1 + d2*d2 + d3*d3;
        eq = eq && (x.x == p.x) && (x.y == p.y) && (x.z == p.z) && (x.w == p.w);
        ushort4 b;
        b.x = f2bf_rne(x.x); b.y = f2bf_rne(x.y); b.z = f2bf_rne(x.z); b.w = f2bf_rne(x.w);
        *(ushort4*)(Xb + (size_t)row * DIM + idx) = b;
    }
    #pragma unroll
    for (int off = 32; off >= 1; off >>= 1) {
        sq += __shfl_xor(sq, off);
        sm += __shfl_xor(sm, off);
        pd += __shfl_xor(pd, off);
    }
    const bool alleq = __all(eq);
    if (lane == 0) {
        cj[row]    = sq - 2.f * EPS * sm;
        basei[row] = sq + 2.f * EPS * sm + (float)DIM * EPS * EPS;
        posd[row]  = sqrtf(pd);
        valid[row] = alleq ? 0 : 1;
    }
}

// ---------------- kernel 2: co-resident symmetric GEMM + row/col max ----------------
// LDS slot = 256 rows x 32 K bf16 = 1024 chunks of 16B (16KB). Swizzle: logical (r,c)
// chunk at phys p = r*4 + (c ^ ((r>>1)&3)). gload_lds writes phys-linear (thread q ->
// chunk q), so source is pre-permuted: thread q fetches row q>>2, K-chunk (q&3)^((q>>3)&3).
__global__ __launch_bounds__(512, 4) void gemm_max_kernel(
        const unsigned short* __restrict__ Xb,
        const float* __restrict__ cj,
        float* __restrict__ partmax)
{
    // [buf][slot: A,B][1024 chunks * 8 ushort]  = 64 KB total
    __shared__ alignas(16) unsigned short lds[2][2][8192];

    const int tid  = threadIdx.x;
    const int lane = tid & 63;
    const int wid  = tid >> 6;        // 0..7
    const int wm   = wid >> 2;        // 0..1  (M half: 128 rows)
    const int wn   = wid & 3;         // 0..3  (N quarter: 64 cols)
    const int l15  = lane & 15;
    const int lk   = lane >> 4;       // 0..3 (K chunk of 8)
    const int cx   = lk ^ ((l15 >> 1) & 3);   // swizzled K-chunk (rows == l15 mod 16)

    // XCD-chunked bijective triangular decode (528 = 8 * 66)
    const int t0 = (blockIdx.x & 7) * (NTRI / 8) + (blockIdx.x >> 3);
    int bm = (int)(32.5f - sqrtf(1056.25f - 2.f * (float)t0));
    if (bm < 0) bm = 0;
    if (bm > NBT - 1) bm = NBT - 1;
    while (bm > 0 && (65 * bm - bm * bm) / 2 > t0) --bm;
    while ((65 * (bm + 1) - (bm + 1) * (bm + 1)) / 2 <= t0) ++bm;
    const int bn = bm + (t0 - (65 * bm - bm * bm) / 2);
    const bool diag = (bm == bn);
    const int Mbase = bm * BT, Nbase = bn * BT;

    f32x4 acc[8][4];
    #pragma unroll
    for (int m = 0; m < 8; ++m)
        #pragma unroll
        for (int n = 0; n < 4; ++n)
            acc[m][n] = (f32x4){0.f, 0.f, 0.f, 0.f};

    // stage one 256x32 matrix tile (2 x global_load_lds of 16B/thread)
    #define STAGE(BUF, SLOT, GBASE, KT) do {                                                  \
        _Pragma("unroll")                                                                     \
        for (int inst_ = 0; inst_ < 2; ++inst_) {                                             \
            const int q_ = inst_ * 512 + tid;                                                 \
            const int r_ = q_ >> 2;                                                           \
            const int c_ = (q_ & 3) ^ ((q_ >> 3) & 3);                                        \
            const unsigned short* src_ = Xb + (size_t)((GBASE) + r_) * DIM + (KT) * BK + c_ * 8; \
            unsigned short* dst_ = &lds[BUF][SLOT][(inst_ * 512 + wid * 64) * 8];             \
            __builtin_amdgcn_global_load_lds((const __attribute__((address_space(1))) void*)src_, \
                                             (__attribute__((address_space(3))) void*)dst_, 16, 0, 0); \
        }                                                                                     \
    } while (0)

    // prologue: stage KT0 into buf0; full drain
    STAGE(0, 0, Mbase, 0); STAGE(0, 1, Nbase, 0);
    __syncthreads();

    #pragma unroll 2
    for (int kt = 0; kt < NKT; ++kt) {
        const int b = kt & 1;
        // prefetch next KT into the other buffer (its reads finished @ previous barrier)
        if (kt + 1 < NKT) { STAGE(b ^ 1, 0, Mbase, kt + 1); STAGE(b ^ 1, 1, Nbase, kt + 1); }

        const unsigned short* Ab = &lds[b][0][0];
        const unsigned short* Bb = &lds[b][1][0];
        short8 af[8], bf[4];
        #pragma unroll
        for (int mt = 0; mt < 8; ++mt)
            af[mt] = *(const short8*)(Ab + (((wm * 128 + mt * 16 + l15) << 2) + cx) * 8);
        #pragma unroll
        for (int nt = 0; nt < 4; ++nt)
            bf[nt] = *(const short8*)(Bb + (((wn * 64 + nt * 16 + l15) << 2) + cx) * 8);

        __builtin_amdgcn_s_setprio(1);
        #pragma unroll
        for (int mt = 0; mt < 8; ++mt)
            #pragma unroll
            for (int nt = 0; nt < 4; ++nt)
                acc[mt][nt] = __builtin_amdgcn_mfma_f32_16x16x32_bf16(af[mt], bf[nt], acc[mt][nt], 0, 0, 0);
        __builtin_amdgcn_s_setprio(0);

        // drains vmcnt(0)+lgkmcnt(0) then barriers: next-KT buffer ready, this buffer free
        __syncthreads();
    }
    #undef STAGE

    // ---- epilogue. C/D layout: col = l15, row = lk*4 + reg. acc[m][n]: row m*16, col n*16.
    // Scratch carved from buf0 (last read at kt=30, two barriers ago):
    float* scratchf = (float*)&lds[0][0][0];   // [0..1023]: partrow[4][256], [1024..1535]: partcol[2][256]
    float cv[4];
    #pragma unroll
    for (int n = 0; n < 4; ++n)
        cv[n] = cj[Nbase + wn * 64 + n * 16 + l15];

    // (a) row-max over this wave's 64 cols, combine across wn via LDS
    #pragma unroll
    for (int m = 0; m < 8; ++m) {
        #pragma unroll
        for (int r = 0; r < 4; ++r) {
            const int lrow = wm * 128 + m * 16 + lk * 4 + r;
            float v = -__builtin_inff();
            #pragma unroll
            for (int n = 0; n < 4; ++n) {
                float val = cv[n] - 2.f * acc[m][n][r];
                if (diag && lrow == wn * 64 + n * 16 + l15) val = -__builtin_inff();
                v = fmaxf(v, val);
            }
            #pragma unroll
            for (int off = 8; off >= 1; off >>= 1)
                v = fmaxf(v, __shfl_xor(v, off));
            if (l15 == 0) scratchf[wn * BT + lrow] = v;
        }
    }

    // (b) transposed col-max over this wave's 128 rows, combine across wm
    if (!diag) {
        float vt[4];
        #pragma unroll
        for (int n = 0; n < 4; ++n) vt[n] = -__builtin_inff();
        #pragma unroll
        for (int m = 0; m < 8; ++m) {
            #pragma unroll
            for (int r = 0; r < 4; ++r) {
                const float ci = cj[Mbase + wm * 128 + m * 16 + lk * 4 + r];
                #pragma unroll
                for (int n = 0; n < 4; ++n)
                    vt[n] = fmaxf(vt[n], ci - 2.f * acc[m][n][r]);
            }
        }
        #pragma unroll
        for (int n = 0; n < 4; ++n) {
            vt[n] = fmaxf(vt[n], __shfl_xor(vt[n], 16));
            vt[n] = fmaxf(vt[n], __shfl_xor(vt[n], 32));
            if (lk == 0) scratchf[4 * BT + wm * BT + wn * 64 + n * 16 + l15] = vt[n];
        }
    }
    __syncthreads();

    if (tid < BT) {
        const float v = fmaxf(fmaxf(scratchf[0 * BT + tid], scratchf[1 * BT + tid]),
                              fmaxf(scratchf[2 * BT + tid], scratchf[3 * BT + tid]));
        partmax[(size_t)bn * NROWS + Mbase + tid] = v;
    } else if (!diag) {
        const int c = tid - BT;
        partmax[(size_t)bm * NROWS + Nbase + c] = fmaxf(scratchf[4 * BT + c], scratchf[5 * BT + c]);
    }
}

// ---------------- kernel 3: per-row finalize + block partial sums ----------------
__global__ void finalize1_kernel(const float* __restrict__ partmax,
                                 const float* __restrict__ basei,
                                 const float* __restrict__ posd,
                                 const int* __restrict__ valid,
                                 float* __restrict__ partials)
{
    const int tid = threadIdx.x;
    const int row = blockIdx.x * 256 + tid;
    float m = -__builtin_inff();
    #pragma unroll 8
    for (int p = 0; p < NBT; ++p)
        m = fmaxf(m, partmax[(size_t)p * NROWS + row]);
    const float d2 = m + basei[row];
    const float mn = sqrtf(fmaxf(d2, 0.f));
    float loss = fmaxf(posd[row] - mn + MARGIN, 0.f);
    float cnt = 1.f;
    if (!valid[row]) { loss = 0.f; cnt = 0.f; }
    #pragma unroll
    for (int off = 32; off >= 1; off >>= 1) {
        loss += __shfl_xor(loss, off);
        cnt  += __shfl_xor(cnt, off);
    }
    __shared__ float sl[4], sc[4];
    const int w = tid >> 6, lane = tid & 63;
    if (lane == 0) { sl[w] = loss; sc[w] = cnt; }
    __syncthreads();
    if (tid == 0) {
        partials[blockIdx.x * 2]     = sl[0] + sl[1] + sl[2] + sl[3];
        partials[blockIdx.x * 2 + 1] = sc[0] + sc[1] + sc[2] + sc[3];
    }
}

// ---------------- kernel 4: final scalar ----------------
__global__ void finalize2_kernel(const float* __restrict__ partials, float* __restrict__ out)
{
    const int tid = threadIdx.x;   // 64 threads
    float l = 0.f, c = 0.f;
    if (tid < 32) { l = partials[tid * 2]; c = partials[tid * 2 + 1]; }
    #pragma unroll
    for (int off = 32; off >= 1; off >>= 1) {
        l += __shfl_xor(l, off);
        c += __shfl_xor(c, off);
    }
    if (tid == 0) out[0] = l / c;
}

extern "C" void kernel_launch(void* const* d_in, const int* in_sizes, int n_in,
                              void* d_out, int out_size, void* d_ws, size_t ws_size,
                              hipStream_t stream)
{
    const float* X = (const float*)d_in[0];   // [8192,1024] f32
    const float* P = (const float*)d_in[1];   // [1024] f32
    float* out = (float*)d_out;
    char* ws = (char*)d_ws;

    unsigned short* Xb = (unsigned short*)ws;                                // 16 MB bf16
    size_t off = (size_t)NROWS * DIM * sizeof(unsigned short);
    float* cj    = (float*)(ws + off);  off += (size_t)NROWS * 4;
    float* basei = (float*)(ws + off);  off += (size_t)NROWS * 4;
    float* posd  = (float*)(ws + off);  off += (size_t)NROWS * 4;
    int*   valid = (int*)(ws + off);    off += (size_t)NROWS * 4;
    float* partmax = (float*)(ws + off); off += (size_t)NBT * NROWS * 4;     // 1 MB
    float* partials = (float*)(ws + off);

    prep_kernel<<<NROWS / 4, 256, 0, stream>>>(X, P, Xb, cj, basei, posd, valid);
    gemm_max_kernel<<<NTRI, 512, 0, stream>>>(Xb, cj, partmax);
    finalize1_kernel<<<NROWS / 256, 256, 0, stream>>>(partmax, basei, posd, valid, partials);
    finalize2_kernel<<<1, 64, 0, stream>>>(partials, out);
}

// Round 9
// 158.901 us; speedup vs baseline: 6.3794x; 6.3794x over previous
//
#include <hip/hip_runtime.h>
#include <hip/hip_bf16.h>

// BatchTripletLoss on MI355X — round 9: single-barrier KT at BK=64, 1 block/CU.
// 256^2 triangular blocks (bn>=bm), 8 waves (2M x 4N), 16x16x32 MFMA, 2 dbuf.
// Per KT: {stage(kt+1 -> other buf, 8 gload_lds); 16 ds_reads; 32 MFMA(lo);
//          8 ds_reads (af reused); 32 MFMA(hi); __syncthreads()}.
// One barrier/KT lets the 2 waves/SIMD drift into read/MFMA complementarity;
// the sync's vmcnt(0) drain is free (prefetch lead = 1 full KT > HBM latency).
// Arch-VGPR kept <=128 (af[] reuse) so 2 waves/SIMD fit the 256-unified budget.
// Both-sides XOR swizzle (phys chunk = r*8 + (c ^ (r&7))); XCD-chunked grid.

#define NROWS 8192
#define DIM   1024
#define BT    256
#define BK    64
#define NKT   (DIM / BK)            // 16 K-tiles
#define NBT   (NROWS / BT)          // 32 tile-rows
#define NTRI  (NBT * (NBT + 1) / 2) // 528 blocks

constexpr float EPS = 1e-6f;
constexpr float MARGIN = 0.5f;

typedef __attribute__((ext_vector_type(8))) short short8;
typedef __attribute__((ext_vector_type(4))) float f32x4;

__device__ __forceinline__ unsigned short f2bf_rne(float f) {
    unsigned u = __float_as_uint(f);
    u += 0x7fffu + ((u >> 16) & 1u);
    return (unsigned short)(u >> 16);
}

// ---------------- kernel 1: per-row stats + bf16 conversion ----------------
__global__ void prep_kernel(const float* __restrict__ X, const float* __restrict__ P,
                            unsigned short* __restrict__ Xb,
                            float* __restrict__ cj, float* __restrict__ basei,
                            float* __restrict__ posd, int* __restrict__ valid)
{
    const int tid  = threadIdx.x;
    const int w    = tid >> 6;
    const int lane = tid & 63;
    const int row  = blockIdx.x * 4 + w;
    const float* xr = X + (size_t)row * DIM;

    float sq = 0.f, sm = 0.f, pd = 0.f;
    bool eq = true;
    #pragma unroll
    for (int it = 0; it < 4; ++it) {
        const int idx = it * 256 + lane * 4;
        const float4 x = *(const float4*)(xr + idx);
        const float4 p = *(const float4*)(P + idx);
        sq += x.x*x.x + x.y*x.y + x.z*x.z + x.w*x.w;
        sm += x.x + x.y + x.z + x.w;
        const float d0 = x.x - p.x + EPS, d1 = x.y - p.y + EPS;
        const float d2 = x.z - p.z + EPS, d3 = x.w - p.w + EPS;
        pd += d0*d0 + d1*d1 + d2*d2 + d3*d3;
        eq = eq && (x.x == p.x) && (x.y == p.y) && (x.z == p.z) && (x.w == p.w);
        ushort4 b;
        b.x = f2bf_rne(x.x); b.y = f2bf_rne(x.y); b.z = f2bf_rne(x.z); b.w = f2bf_rne(x.w);
        *(ushort4*)(Xb + (size_t)row * DIM + idx) = b;
    }
    #pragma unroll
    for (int off = 32; off >= 1; off >>= 1) {
        sq += __shfl_xor(sq, off);
        sm += __shfl_xor(sm, off);
        pd += __shfl_xor(pd, off);
    }
    const bool alleq = __all(eq);
    if (lane == 0) {
        cj[row]    = sq - 2.f * EPS * sm;
        basei[row] = sq + 2.f * EPS * sm + (float)DIM * EPS * EPS;
        posd[row]  = sqrtf(pd);
        valid[row] = alleq ? 0 : 1;
    }
}

// ---------------- kernel 2: single-barrier-KT symmetric GEMM + row/col max ----------------
// LDS slot = 256 rows x 64 K bf16 = 2048 chunks of 16B (32 KB). Swizzle: logical (r,c)
// chunk at phys p = r*8 + (c ^ (r&7)). gload_lds writes phys-linear (thread q -> chunk q
// within its inst group), so source is pre-permuted: row q>>3, K-chunk (q&7)^((q>>3)&7).
__global__ __launch_bounds__(512, 2) void gemm_max_kernel(
        const unsigned short* __restrict__ Xb,
        const float* __restrict__ cj,
        float* __restrict__ partmax)
{
    // [buf][slot: A,B][2048 chunks * 8 ushort] = 128 KB
    __shared__ alignas(16) unsigned short lds[2][2][16384];
    __shared__ float partrow[4][BT];
    __shared__ float partcol[2][BT];

    const int tid  = threadIdx.x;
    const int lane = tid & 63;
    const int wid  = tid >> 6;        // 0..7
    const int wm   = wid >> 2;        // 0..1  (M half: 128 rows)
    const int wn   = wid & 3;         // 0..3  (N quarter: 64 cols)
    const int l15  = lane & 15;
    const int lk   = lane >> 4;       // 0..3
    const int cx0  = lk ^ (l15 & 7);          // K-chunk for ks=0
    const int cx1  = (4 + lk) ^ (l15 & 7);    // ks=1

    // XCD-chunked bijective triangular decode (528 = 8 * 66)
    const int t0 = (blockIdx.x & 7) * (NTRI / 8) + (blockIdx.x >> 3);
    int bm = (int)(32.5f - sqrtf(1056.25f - 2.f * (float)t0));
    if (bm < 0) bm = 0;
    if (bm > NBT - 1) bm = NBT - 1;
    while (bm > 0 && (65 * bm - bm * bm) / 2 > t0) --bm;
    while ((65 * (bm + 1) - (bm + 1) * (bm + 1)) / 2 <= t0) ++bm;
    const int bn = bm + (t0 - (65 * bm - bm * bm) / 2);
    const bool diag = (bm == bn);
    const int Mbase = bm * BT, Nbase = bn * BT;

    f32x4 acc[8][4];
    #pragma unroll
    for (int m = 0; m < 8; ++m)
        #pragma unroll
        for (int n = 0; n < 4; ++n)
            acc[m][n] = (f32x4){0.f, 0.f, 0.f, 0.f};

    // stage one 256x64 matrix tile (4 x global_load_lds of 16B/thread)
    #define STAGE(BUF, SLOT, GBASE, KT) do {                                                  \
        _Pragma("unroll")                                                                     \
        for (int inst_ = 0; inst_ < 4; ++inst_) {                                             \
            const int q_ = inst_ * 512 + tid;                                                 \
            const int r_ = q_ >> 3;                                                           \
            const int c_ = (q_ & 7) ^ (r_ & 7);                                               \
            const unsigned short* src_ = Xb + (size_t)((GBASE) + r_) * DIM + (KT) * BK + c_ * 8; \
            unsigned short* dst_ = &lds[BUF][SLOT][(inst_ * 512 + wid * 64) * 8];             \
            __builtin_amdgcn_global_load_lds((const __attribute__((address_space(1))) void*)src_, \
                                             (__attribute__((address_space(3))) void*)dst_, 16, 0, 0); \
        }                                                                                     \
    } while (0)

    // prologue: stage KT0 into buf0; full drain
    STAGE(0, 0, Mbase, 0); STAGE(0, 1, Nbase, 0);
    __syncthreads();

    #pragma unroll 2
    for (int kt = 0; kt < NKT; ++kt) {
        const int b = kt & 1;
        // prefetch next KT into the other buffer (its reads finished @ previous sync)
        if (kt + 1 < NKT) { STAGE(b ^ 1, 0, Mbase, kt + 1); STAGE(b ^ 1, 1, Nbase, kt + 1); }

        const unsigned short* Ab = &lds[b][0][0];
        const unsigned short* Bb = &lds[b][1][0];
        short8 af[8], bf0[4], bf1[4];

        // reads: af_lo(8) + bf0(4) + bf1(4)
        #pragma unroll
        for (int mt = 0; mt < 4; ++mt) {
            const int row = wm * 128 + mt * 16 + l15;
            af[mt * 2]     = *(const short8*)(Ab + (row * 8 + cx0) * 8);
            af[mt * 2 + 1] = *(const short8*)(Ab + (row * 8 + cx1) * 8);
        }
        #pragma unroll
        for (int nt = 0; nt < 2; ++nt) {
            const int rowb = wn * 64 + nt * 16 + l15;
            bf0[nt * 2]     = *(const short8*)(Bb + (rowb * 8 + cx0) * 8);
            bf0[nt * 2 + 1] = *(const short8*)(Bb + (rowb * 8 + cx1) * 8);
            const int rowb1 = wn * 64 + 32 + nt * 16 + l15;
            bf1[nt * 2]     = *(const short8*)(Bb + (rowb1 * 8 + cx0) * 8);
            bf1[nt * 2 + 1] = *(const short8*)(Bb + (rowb1 * 8 + cx1) * 8);
        }

        // MFMA lo: Q(lo, n01) then Q(lo, n23)
        __builtin_amdgcn_s_setprio(1);
        #pragma unroll
        for (int ks = 0; ks < 2; ++ks)
            #pragma unroll
            for (int mt = 0; mt < 4; ++mt)
                #pragma unroll
                for (int nt = 0; nt < 2; ++nt)
                    acc[mt][nt] = __builtin_amdgcn_mfma_f32_16x16x32_bf16(af[mt*2+ks], bf0[nt*2+ks], acc[mt][nt], 0, 0, 0);
        #pragma unroll
        for (int ks = 0; ks < 2; ++ks)
            #pragma unroll
            for (int mt = 0; mt < 4; ++mt)
                #pragma unroll
                for (int nt = 0; nt < 2; ++nt)
                    acc[mt][2+nt] = __builtin_amdgcn_mfma_f32_16x16x32_bf16(af[mt*2+ks], bf1[nt*2+ks], acc[mt][2+nt], 0, 0, 0);
        __builtin_amdgcn_s_setprio(0);

        // reads: af_hi(8) — reuse af[] to keep arch-VGPR <= 128
        #pragma unroll
        for (int mt = 0; mt < 4; ++mt) {
            const int row = wm * 128 + 64 + mt * 16 + l15;
            af[mt * 2]     = *(const short8*)(Ab + (row * 8 + cx0) * 8);
            af[mt * 2 + 1] = *(const short8*)(Ab + (row * 8 + cx1) * 8);
        }

        // MFMA hi: Q(hi, n01) then Q(hi, n23)
        __builtin_amdgcn_s_setprio(1);
        #pragma unroll
        for (int ks = 0; ks < 2; ++ks)
            #pragma unroll
            for (int mt = 0; mt < 4; ++mt)
                #pragma unroll
                for (int nt = 0; nt < 2; ++nt)
                    acc[4+mt][nt] = __builtin_amdgcn_mfma_f32_16x16x32_bf16(af[mt*2+ks], bf0[nt*2+ks], acc[4+mt][nt], 0, 0, 0);
        #pragma unroll
        for (int ks = 0; ks < 2; ++ks)
            #pragma unroll
            for (int mt = 0; mt < 4; ++mt)
                #pragma unroll
                for (int nt = 0; nt < 2; ++nt)
                    acc[4+mt][2+nt] = __builtin_amdgcn_mfma_f32_16x16x32_bf16(af[mt*2+ks], bf1[nt*2+ks], acc[4+mt][2+nt], 0, 0, 0);
        __builtin_amdgcn_s_setprio(0);

        // one barrier per KT: drains vmcnt(0)+lgkmcnt(0), flips buffers
        __syncthreads();
    }
    #undef STAGE

    // ---- epilogue. C/D layout: col = l15, row = lk*4 + reg. acc[m][n]: row wm*128+m*16, col wn*64+n*16
    float cv[4];
    #pragma unroll
    for (int n = 0; n < 4; ++n)
        cv[n] = cj[Nbase + wn * 64 + n * 16 + l15];

    // (a) row-max over this wave's 64 cols, combine across wn via LDS
    #pragma unroll
    for (int m = 0; m < 8; ++m) {
        #pragma unroll
        for (int r = 0; r < 4; ++r) {
            const int lrow = wm * 128 + m * 16 + lk * 4 + r;
            float v = -__builtin_inff();
            #pragma unroll
            for (int n = 0; n < 4; ++n) {
                float val = cv[n] - 2.f * acc[m][n][r];
                if (diag && lrow == wn * 64 + n * 16 + l15) val = -__builtin_inff();
                v = fmaxf(v, val);
            }
            #pragma unroll
            for (int off = 8; off >= 1; off >>= 1)
                v = fmaxf(v, __shfl_xor(v, off));
            if (l15 == 0) partrow[wn][lrow] = v;
        }
    }

    // (b) transposed col-max over this wave's 128 rows, combine across wm
    if (!diag) {
        float vt[4];
        #pragma unroll
        for (int n = 0; n < 4; ++n) vt[n] = -__builtin_inff();
        #pragma unroll
        for (int m = 0; m < 8; ++m) {
            #pragma unroll
            for (int r = 0; r < 4; ++r) {
                const float ci = cj[Mbase + wm * 128 + m * 16 + lk * 4 + r];
                #pragma unroll
                for (int n = 0; n < 4; ++n)
                    vt[n] = fmaxf(vt[n], ci - 2.f * acc[m][n][r]);
            }
        }
        #pragma unroll
        for (int n = 0; n < 4; ++n) {
            vt[n] = fmaxf(vt[n], __shfl_xor(vt[n], 16));
            vt[n] = fmaxf(vt[n], __shfl_xor(vt[n], 32));
            if (lk == 0) partcol[wm][wn * 64 + n * 16 + l15] = vt[n];
        }
    }
    __syncthreads();

    if (tid < BT) {
        const float v = fmaxf(fmaxf(partrow[0][tid], partrow[1][tid]),
                              fmaxf(partrow[2][tid], partrow[3][tid]));
        partmax[(size_t)bn * NROWS + Mbase + tid] = v;
    } else if (!diag) {
        const int c = tid - BT;
        partmax[(size_t)bm * NROWS + Nbase + c] = fmaxf(partcol[0][c], partcol[1][c]);
    }
}

// ---------------- kernel 3: per-row finalize + block partial sums ----------------
__global__ void finalize1_kernel(const float* __restrict__ partmax,
                                 const float* __restrict__ basei,
                                 const float* __restrict__ posd,
                                 const int* __restrict__ valid,
                                 float* __restrict__ partials)
{
    const int tid = threadIdx.x;
    const int row = blockIdx.x * 256 + tid;
    float m = -__builtin_inff();
    #pragma unroll 8
    for (int p = 0; p < NBT; ++p)
        m = fmaxf(m, partmax[(size_t)p * NROWS + row]);
    const float d2 = m + basei[row];
    const float mn = sqrtf(fmaxf(d2, 0.f));
    float loss = fmaxf(posd[row] - mn + MARGIN, 0.f);
    float cnt = 1.f;
    if (!valid[row]) { loss = 0.f; cnt = 0.f; }
    #pragma unroll
    for (int off = 32; off >= 1; off >>= 1) {
        loss += __shfl_xor(loss, off);
        cnt  += __shfl_xor(cnt, off);
    }
    __shared__ float sl[4], sc[4];
    const int w = tid >> 6, lane = tid & 63;
    if (lane == 0) { sl[w] = loss; sc[w] = cnt; }
    __syncthreads();
    if (tid == 0) {
        partials[blockIdx.x * 2]     = sl[0] + sl[1] + sl[2] + sl[3];
        partials[blockIdx.x * 2 + 1] = sc[0] + sc[1] + sc[2] + sc[3];
    }
}

// ---------------- kernel 4: final scalar ----------------
__global__ void finalize2_kernel(const float* __restrict__ partials, float* __restrict__ out)
{
    const int tid = threadIdx.x;   // 64 threads
    float l = 0.f, c = 0.f;
    if (tid < 32) { l = partials[tid * 2]; c = partials[tid * 2 + 1]; }
    #pragma unroll
    for (int off = 32; off >= 1; off >>= 1) {
        l += __shfl_xor(l, off);
        c += __shfl_xor(c, off);
    }
    if (tid == 0) out[0] = l / c;
}

extern "C" void kernel_launch(void* const* d_in, const int* in_sizes, int n_in,
                              void* d_out, int out_size, void* d_ws, size_t ws_size,
                              hipStream_t stream)
{
    const float* X = (const float*)d_in[0];   // [8192,1024] f32
    const float* P = (const float*)d_in[1];   // [1024] f32
    float* out = (float*)d_out;
    char* ws = (char*)d_ws;

    unsigned short* Xb = (unsigned short*)ws;                                // 16 MB bf16
    size_t off = (size_t)NROWS * DIM * sizeof(unsigned short);
    float* cj    = (float*)(ws + off);  off += (size_t)NROWS * 4;
    float* basei = (float*)(ws + off);  off += (size_t)NROWS * 4;
    float* posd  = (float*)(ws + off);  off += (size_t)NROWS * 4;
    int*   valid = (int*)(ws + off);    off += (size_t)NROWS * 4;
    float* partmax = (float*)(ws + off); off += (size_t)NBT * NROWS * 4;     // 1 MB
    float* partials = (float*)(ws + off);

    prep_kernel<<<NROWS / 4, 256, 0, stream>>>(X, P, Xb, cj, basei, posd, valid);
    gemm_max_kernel<<<NTRI, 512, 0, stream>>>(Xb, cj, partmax);
    finalize1_kernel<<<NROWS / 256, 256, 0, stream>>>(partmax, basei, posd, valid, partials);
    finalize2_kernel<<<1, 64, 0, stream>>>(partials, out);
}

// Round 10
// 118.512 us; speedup vs baseline: 8.5535x; 1.3408x over previous
//
#include <hip/hip_runtime.h>
#include <hip/hip_bf16.h>

// BatchTripletLoss on MI355X — round 10: 2-blocks/CU co-residency via small tiles.
// Units: 256x128 (bm in [0,32) x bn in [0,64), include iff bn >= 2*bm -> 1056 units).
// 8 waves (4M x 2N), per-wave 64x64 -> acc = 64 AGPR; BK=32 double-buffer = 48KB LDS;
// __launch_bounds__(512,4) -> 4 waves/SIMD -> 2 blocks/CU co-resident (overlap pipes,
// m114) + finer grid kills the dispatch tail (1056 = 8*132, exact XCD chunking).
// Per KT: {stage(kt+1 -> other buf, 3 gload_lds); 8 ds_reads; 16 MFMA; __syncthreads}.
// Coverage: every pair {i,j}, i<j lies in unit (i/256, j/128) since j/128 >= 2*(i/256);
// units also contain i>j cells -> duplicates, harmless under max; mask i==j only.
// Row-path slot bn: max over unit cols for its 256 rows; col-path slot 64+bm: max over
// unit rows for its 128 cols. Finalize: row i reads bn in [2*(i>>8), 64) and bm in [0, i>>8].

#define NROWS 8192
#define DIM   1024
#define BTM   256
#define BTN   128
#define BK    32
#define NKT   (DIM / BK)            // 32 K-tiles
#define NUNITS 1056                 // sum_{bm<32} (64 - 2*bm)

constexpr float EPS = 1e-6f;
constexpr float MARGIN = 0.5f;

typedef __attribute__((ext_vector_type(8))) short short8;
typedef __attribute__((ext_vector_type(4))) float f32x4;

__device__ __forceinline__ unsigned short f2bf_rne(float f) {
    unsigned u = __float_as_uint(f);
    u += 0x7fffu + ((u >> 16) & 1u);
    return (unsigned short)(u >> 16);
}

// ---------------- kernel 1: per-row stats + bf16 conversion ----------------
__global__ void prep_kernel(const float* __restrict__ X, const float* __restrict__ P,
                            unsigned short* __restrict__ Xb,
                            float* __restrict__ cj, float* __restrict__ basei,
                            float* __restrict__ posd, int* __restrict__ valid)
{
    const int tid  = threadIdx.x;
    const int w    = tid >> 6;
    const int lane = tid & 63;
    const int row  = blockIdx.x * 4 + w;
    const float* xr = X + (size_t)row * DIM;

    float sq = 0.f, sm = 0.f, pd = 0.f;
    bool eq = true;
    #pragma unroll
    for (int it = 0; it < 4; ++it) {
        const int idx = it * 256 + lane * 4;
        const float4 x = *(const float4*)(xr + idx);
        const float4 p = *(const float4*)(P + idx);
        sq += x.x*x.x + x.y*x.y + x.z*x.z + x.w*x.w;
        sm += x.x + x.y + x.z + x.w;
        const float d0 = x.x - p.x + EPS, d1 = x.y - p.y + EPS;
        const float d2 = x.z - p.z + EPS, d3 = x.w - p.w + EPS;
        pd += d0*d0 + d1*d1 + d2*d2 + d3*d3;
        eq = eq && (x.x == p.x) && (x.y == p.y) && (x.z == p.z) && (x.w == p.w);
        ushort4 b;
        b.x = f2bf_rne(x.x); b.y = f2bf_rne(x.y); b.z = f2bf_rne(x.z); b.w = f2bf_rne(x.w);
        *(ushort4*)(Xb + (size_t)row * DIM + idx) = b;
    }
    #pragma unroll
    for (int off = 32; off >= 1; off >>= 1) {
        sq += __shfl_xor(sq, off);
        sm += __shfl_xor(sm, off);
        pd += __shfl_xor(pd, off);
    }
    const bool alleq = __all(eq);
    if (lane == 0) {
        cj[row]    = sq - 2.f * EPS * sm;
        basei[row] = sq + 2.f * EPS * sm + (float)DIM * EPS * EPS;
        posd[row]  = sqrtf(pd);
        valid[row] = alleq ? 0 : 1;
    }
}

// ---------------- kernel 2: co-resident symmetric GEMM + row/col max ----------------
// LDS: per buf, A = 256 rows x 32 K = 1024 chunks of 16B (16KB), B = 128 rows = 512
// chunks (8KB). Swizzle: logical (r,c) chunk at phys p = r*4 + (c ^ ((r>>1)&3));
// gload_lds writes phys-linear, so source pre-permuted: thread q -> row q>>2,
// K-chunk (q&3)^((q>>3)&3). Frag reads at 16-row-aligned bases: cx = lk ^ ((l15>>1)&3)
// -> 2 lanes/bank-granule (free).
__global__ __launch_bounds__(512, 4) void gemm_max_kernel(
        const unsigned short* __restrict__ Xb,
        const float* __restrict__ cj,
        float* __restrict__ partmax)
{
    __shared__ alignas(16) unsigned short lds[2][1536 * 8];   // [buf][A:0..1023 | B:1024..1535 chunks]

    const int tid  = threadIdx.x;
    const int lane = tid & 63;
    const int wid  = tid >> 6;        // 0..7
    const int wm   = wid >> 1;        // 0..3  (64-row strip)
    const int wn   = wid & 1;         // 0..1  (64-col strip)
    const int l15  = lane & 15;
    const int lk   = lane >> 4;       // 0..3
    const int cx   = lk ^ ((l15 >> 1) & 3);

    // XCD-chunked bijective unit decode (1056 = 8 * 132); base(bm) = 65*bm - bm*bm
    const int t0 = (blockIdx.x & 7) * (NUNITS / 8) + (blockIdx.x >> 3);
    int bm = (int)(32.5f - sqrtf(1056.25f - (float)t0));
    if (bm < 0) bm = 0;
    if (bm > 31) bm = 31;
    while (bm > 0 && 65 * bm - bm * bm > t0) --bm;
    while (65 * (bm + 1) - (bm + 1) * (bm + 1) <= t0) ++bm;
    const int bn = 2 * bm + (t0 - (65 * bm - bm * bm));
    const int Mbase = bm * BTM, Nbase = bn * BTN;

    f32x4 acc[4][4];
    #pragma unroll
    for (int m = 0; m < 4; ++m)
        #pragma unroll
        for (int n = 0; n < 4; ++n)
            acc[m][n] = (f32x4){0.f, 0.f, 0.f, 0.f};

    // stage A (2 insts) + B (1 inst) for one KT into buffer BUF
    #define STAGE(BUF, KT) do {                                                               \
        _Pragma("unroll")                                                                     \
        for (int inst_ = 0; inst_ < 2; ++inst_) {                                             \
            const int q_ = inst_ * 512 + tid;                                                 \
            const int r_ = q_ >> 2;                                                           \
            const int c_ = (q_ & 3) ^ ((q_ >> 3) & 3);                                        \
            const unsigned short* src_ = Xb + (size_t)(Mbase + r_) * DIM + (KT) * BK + c_ * 8; \
            unsigned short* dst_ = &lds[BUF][(inst_ * 512 + wid * 64) * 8];                   \
            __builtin_amdgcn_global_load_lds((const __attribute__((address_space(1))) void*)src_, \
                                             (__attribute__((address_space(3))) void*)dst_, 16, 0, 0); \
        }                                                                                     \
        {                                                                                     \
            const int r_ = tid >> 2;                                                          \
            const int c_ = (tid & 3) ^ ((tid >> 3) & 3);                                      \
            const unsigned short* src_ = Xb + (size_t)(Nbase + r_) * DIM + (KT) * BK + c_ * 8; \
            unsigned short* dst_ = &lds[BUF][(1024 + wid * 64) * 8];                          \
            __builtin_amdgcn_global_load_lds((const __attribute__((address_space(1))) void*)src_, \
                                             (__attribute__((address_space(3))) void*)dst_, 16, 0, 0); \
        }                                                                                     \
    } while (0)

    STAGE(0, 0);
    __syncthreads();

    #pragma unroll 2
    for (int kt = 0; kt < NKT; ++kt) {
        const int b = kt & 1;
        if (kt + 1 < NKT) STAGE(b ^ 1, kt + 1);

        const unsigned short* Ab = &lds[b][0];
        const unsigned short* Bb = &lds[b][1024 * 8];
        short8 af[4], bf[4];
        #pragma unroll
        for (int mt = 0; mt < 4; ++mt)
            af[mt] = *(const short8*)(Ab + (((wm * 64 + mt * 16 + l15) << 2) + cx) * 8);
        #pragma unroll
        for (int nt = 0; nt < 4; ++nt)
            bf[nt] = *(const short8*)(Bb + (((wn * 64 + nt * 16 + l15) << 2) + cx) * 8);

        __builtin_amdgcn_s_setprio(1);
        #pragma unroll
        for (int mt = 0; mt < 4; ++mt)
            #pragma unroll
            for (int nt = 0; nt < 4; ++nt)
                acc[mt][nt] = __builtin_amdgcn_mfma_f32_16x16x32_bf16(af[mt], bf[nt], acc[mt][nt], 0, 0, 0);
        __builtin_amdgcn_s_setprio(0);

        __syncthreads();   // drains vmcnt+lgkmcnt; flips buffers
    }
    #undef STAGE

    // ---- epilogue. C/D layout: col = l15, row = lk*4 + reg.
    // acc[m][n]: row wm*64 + m*16, col wn*64 + n*16. Mask only i==j; both paths always.
    float* scratchf = (float*)&lds[0][0];  // [0..511]: row (wn*256+lrow); [512..1023]: col (wm*128+lcol)
    float cv[4];
    #pragma unroll
    for (int n = 0; n < 4; ++n)
        cv[n] = cj[Nbase + wn * 64 + n * 16 + l15];

    float vt[4];
    #pragma unroll
    for (int n = 0; n < 4; ++n) vt[n] = -__builtin_inff();

    #pragma unroll
    for (int m = 0; m < 4; ++m) {
        #pragma unroll
        for (int r = 0; r < 4; ++r) {
            const int lrow = wm * 64 + m * 16 + lk * 4 + r;
            const int grow = Mbase + lrow;
            const float ci = cj[grow];
            float rv = -__builtin_inff();
            #pragma unroll
            for (int n = 0; n < 4; ++n) {
                const float dot2 = 2.f * acc[m][n][r];
                const bool dg = (grow == Nbase + wn * 64 + n * 16 + l15);
                float vr = cv[n] - dot2;
                float vc = ci - dot2;
                if (dg) { vr = -__builtin_inff(); vc = -__builtin_inff(); }
                rv = fmaxf(rv, vr);
                vt[n] = fmaxf(vt[n], vc);
            }
            #pragma unroll
            for (int off = 8; off >= 1; off >>= 1)
                rv = fmaxf(rv, __shfl_xor(rv, off));
            if (l15 == 0) scratchf[wn * 256 + lrow] = rv;
        }
    }
    #pragma unroll
    for (int n = 0; n < 4; ++n) {
        vt[n] = fmaxf(vt[n], __shfl_xor(vt[n], 16));
        vt[n] = fmaxf(vt[n], __shfl_xor(vt[n], 32));
        if (lk == 0) scratchf[512 + wm * 128 + wn * 64 + n * 16 + l15] = vt[n];
    }
    __syncthreads();

    if (tid < BTM) {
        partmax[(size_t)bn * NROWS + Mbase + tid] = fmaxf(scratchf[tid], scratchf[256 + tid]);
    } else if (tid < BTM + BTN) {
        const int c = tid - BTM;
        const float v = fmaxf(fmaxf(scratchf[512 + c], scratchf[640 + c]),
                              fmaxf(scratchf[768 + c], scratchf[896 + c]));
        partmax[(size_t)(64 + bm) * NROWS + Nbase + c] = v;
    }
}

// ---------------- kernel 3: per-row finalize + block partial sums ----------------
// Row i: valid slots are bn in [2*(i>>8), 64) (row-path) and 64+bm, bm in [0, i>>8]
// (col-path). Loop bounds are uniform per 256-row block.
__global__ void finalize1_kernel(const float* __restrict__ partmax,
                                 const float* __restrict__ basei,
                                 const float* __restrict__ posd,
                                 const int* __restrict__ valid,
                                 float* __restrict__ partials)
{
    const int tid = threadIdx.x;
    const int a   = blockIdx.x;          // 256-row strip = bm index of this row
    const int row = a * 256 + tid;
    float m = -__builtin_inff();
    for (int bn = 2 * a; bn < 64; ++bn)
        m = fmaxf(m, partmax[(size_t)bn * NROWS + row]);
    for (int bm2 = 0; bm2 <= a; ++bm2)
        m = fmaxf(m, partmax[(size_t)(64 + bm2) * NROWS + row]);
    const float d2 = m + basei[row];
    const float mn = sqrtf(fmaxf(d2, 0.f));
    float loss = fmaxf(posd[row] - mn + MARGIN, 0.f);
    float cnt = 1.f;
    if (!valid[row]) { loss = 0.f; cnt = 0.f; }
    #pragma unroll
    for (int off = 32; off >= 1; off >>= 1) {
        loss += __shfl_xor(loss, off);
        cnt  += __shfl_xor(cnt, off);
    }
    __shared__ float sl[4], sc[4];
    const int w = tid >> 6, lane = tid & 63;
    if (lane == 0) { sl[w] = loss; sc[w] = cnt; }
    __syncthreads();
    if (tid == 0) {
        partials[blockIdx.x * 2]     = sl[0] + sl[1] + sl[2] + sl[3];
        partials[blockIdx.x * 2 + 1] = sc[0] + sc[1] + sc[2] + sc[3];
    }
}

// ---------------- kernel 4: final scalar ----------------
__global__ void finalize2_kernel(const float* __restrict__ partials, float* __restrict__ out)
{
    const int tid = threadIdx.x;   // 64 threads
    float l = 0.f, c = 0.f;
    if (tid < 32) { l = partials[tid * 2]; c = partials[tid * 2 + 1]; }
    #pragma unroll
    for (int off = 32; off >= 1; off >>= 1) {
        l += __shfl_xor(l, off);
        c += __shfl_xor(c, off);
    }
    if (tid == 0) out[0] = l / c;
}

extern "C" void kernel_launch(void* const* d_in, const int* in_sizes, int n_in,
                              void* d_out, int out_size, void* d_ws, size_t ws_size,
                              hipStream_t stream)
{
    const float* X = (const float*)d_in[0];   // [8192,1024] f32
    const float* P = (const float*)d_in[1];   // [1024] f32
    float* out = (float*)d_out;
    char* ws = (char*)d_ws;

    unsigned short* Xb = (unsigned short*)ws;                                // 16 MB bf16
    size_t off = (size_t)NROWS * DIM * sizeof(unsigned short);
    float* cj    = (float*)(ws + off);  off += (size_t)NROWS * 4;
    float* basei = (float*)(ws + off);  off += (size_t)NROWS * 4;
    float* posd  = (float*)(ws + off);  off += (size_t)NROWS * 4;
    int*   valid = (int*)(ws + off);    off += (size_t)NROWS * 4;
    float* partmax = (float*)(ws + off); off += (size_t)96 * NROWS * 4;      // 3 MB
    float* partials = (float*)(ws + off);

    prep_kernel<<<NROWS / 4, 256, 0, stream>>>(X, P, Xb, cj, basei, posd, valid);
    gemm_max_kernel<<<NUNITS, 512, 0, stream>>>(Xb, cj, partmax);
    finalize1_kernel<<<NROWS / 256, 256, 0, stream>>>(partmax, basei, posd, valid, partials);
    finalize2_kernel<<<1, 64, 0, stream>>>(partials, out);
}